// Round 15
// baseline (71.657 us; speedup 1.0000x reference)
//
#include <hip/hip_runtime.h>
#include <hip/hip_bf16.h>

// z[b,c,m] = sum_d S[m,c,d] * (x[b,d,m] - mean[d,m])
// B=1024, C=64, M=512. x:(B,C,M) f32, mean:(1,C,M), S:(M,C,C), out f32.
//
// v13 = v12 with z DOUBLE-buffer: ZR(T-1) joins the main phase (reads the
// buffer ZW(T) is not writing), leaving STAGE alone in a short P2.
//   P1:[ISSUE(T+2), Bf(T), MFMA, ZW(T->zb[T&1]), ZR(T-1)+stores] BAR
//   P2:[STAGE(T+1)] BAR
// One x buffer (32 KB) + two z buffers (2x64 KB) = 163840 B = full LDS pool.
// Occupancy is register-capped at 16 waves/CU (60 VGPR + ~48 AGPR) anyway.

typedef __attribute__((ext_vector_type(8))) short short8;
typedef __attribute__((ext_vector_type(4))) float f32x4;

namespace {
constexpr int Mm = 512, Cc = 64, Bb = 1024;
constexpr int MT = 16, BT = 16, NB = 8;
constexpr size_t LDSB = 32768 + 2 * 65536;  // 163840 B (full 160 KiB pool)

__device__ __forceinline__ short bfc(float f) {  // f32 -> bf16 RNE (HW cvt)
  __hip_bfloat16 h = __float2bfloat16(f);
  union { __hip_bfloat16 b; short s; } u;
  u.b = h;
  return u.s;
}
__device__ __forceinline__ unsigned pack2(float a, float b) {
  return (unsigned)(unsigned short)bfc(a) |
         ((unsigned)(unsigned short)bfc(b) << 16);
}
// x-LDS chunk swizzle (audited 2-way max on both sides)
__device__ __forceinline__ int xsw(int row, int c) {
  return c ^ (row & 7) ^ (((row >> 6) & 3) << 1);
}
}  // namespace

#define ELEM(V, I) ((I) == 0 ? (V).x : (I) == 1 ? (V).y : (I) == 2 ? (V).z : (V).w)

__global__ __launch_bounds__(1024, 4) void zca_v13(
    const float* __restrict__ x, const float* __restrict__ mean,
    const float* __restrict__ S, float* __restrict__ out) {
  extern __shared__ unsigned char lds[];
  unsigned char* xl = lds;             // 32 KB bf16 x tile (single buffer)
  float* zb0 = (float*)(lds + 32768);  // 64 KB z tile, buffer 0
  float* zb1 = (float*)(lds + 98304);  // 64 KB z tile, buffer 1

  const int tid = threadIdx.x;
  const int l = tid & 63;
  const int w = __builtin_amdgcn_readfirstlane(tid >> 6);  // 0..15 = m_local

  // bijective XCD swizzle: 256 blocks; per XCD 4 m-tiles x 8 b-groups
  const int id = blockIdx.x;
  const int sw = ((id & 7) << 5) + (id >> 3);
  const int m0 = (sw >> 3) * MT;
  const int b0 = (sw & 7) * (BT * NB);

  // staging coords: thread covers (d2,d2+1) x {bq, 8+bq} x 4 m
  const int mq = tid & 3;
  const int u = (tid >> 2) & 15;
  const int bq = w >> 1;
  const int d2 = ((w & 1) << 5) + (u << 1);
  const int chunkS = ((w & 1) << 2) + (u >> 2);
  // z-read coords: quad lanes = 4 m-quads of same (c,b)
  const int mqr = tid & 3;
  const int br = (tid >> 2) & 15;
  const int clow = (tid >> 6) & 15;  // == w

  float4 st0[4], st1[4];

#define ISSUE(ST, T)                                                          \
  {                                                                           \
    _Pragma("unroll") for (int dd = 0; dd < 2; ++dd)                          \
        _Pragma("unroll") for (int p = 0; p < 2; ++p)                         \
            ST[dd * 2 + p] = *(const float4*)(                                \
                x + (size_t)((b0 + (T)*BT + p * 8 + bq) * Cc + d2 + dd) * Mm  \
                  + m0 + mq * 4);                                             \
  }

#define STAGE(ST)                                                             \
  {                                                                           \
    _Pragma("unroll") for (int p = 0; p < 2; ++p) {                           \
      _Pragma("unroll") for (int i = 0; i < 4; ++i) {                         \
        const int row = (mq * 4 + i) * BT + p * 8 + bq;                       \
        const unsigned v = pack2(ELEM(ST[p], i) - ELEM(mvE, i),               \
                                 ELEM(ST[2 + p], i) - ELEM(mvO, i));          \
        *(unsigned*)(xl + row * 128 + xsw(row, chunkS) * 16 + (u & 3) * 4)    \
            = v;                                                              \
      }                                                                       \
    }                                                                         \
  }

#define BAR()                                          \
  {                                                    \
    asm volatile("s_waitcnt lgkmcnt(0)" ::: "memory"); \
    __builtin_amdgcn_s_barrier();                      \
  }

  // ---- prologue ----
  ISSUE(st0, 0)
  ISSUE(st1, 1)
  const float4 mvE = *(const float4*)(mean + (size_t)d2 * Mm + m0 + mq * 4);
  const float4 mvO =
      *(const float4*)(mean + (size_t)(d2 + 1) * Mm + m0 + mq * 4);

  short8 A[4][2];
#pragma unroll
  for (int ct = 0; ct < 4; ++ct) {
#pragma unroll
    for (int ks = 0; ks < 2; ++ks) {
      const float* sp = S + ((size_t)(m0 + w) * Cc + ct * 16 + (l & 15)) * Cc +
                        ks * 32 + (l >> 4) * 8;
      const float4 f0 = *(const float4*)sp;
      const float4 f1 = *(const float4*)(sp + 4);
      short8 a;
      a[0] = bfc(f0.x); a[1] = bfc(f0.y); a[2] = bfc(f0.z); a[3] = bfc(f0.w);
      a[4] = bfc(f1.x); a[5] = bfc(f1.y); a[6] = bfc(f1.z); a[7] = bfc(f1.w);
      A[ct][ks] = a;
    }
  }
  STAGE(st0)
  BAR()

  // ZW: wave w owns m-slice w. vcol = (r ^ h ^ (w>>2)) & 3 -> 2-way banks.
#define ZW(ZB)                                                                \
  {                                                                           \
    const int h = l >> 4;                                                     \
    _Pragma("unroll") for (int ct = 0; ct < 4; ++ct) {                        \
      _Pragma("unroll") for (int r = 0; r < 4; ++r) {                         \
        const int vcol = (r ^ h ^ (w >> 2)) & 3;                              \
        (ZB)[w * 1024 + ct * 256 + h * 64 + vcol * 16 + (l & 15)] =           \
            acc[ct][r];                                                       \
      }                                                                       \
    }                                                                         \
  }

  // ZR: tile TR; thread (mqr, br, clow); 4 c's, each float4-over-m via 4 b32.
#define ZR(ZB, TR)                                                            \
  {                                                                           \
    _Pragma("unroll") for (int t2 = 0; t2 < 4; ++t2) {                        \
      const int c_ = t2 * 16 + clow;                                          \
      const int h = (c_ >> 2) & 3, r = c_ & 3;                                \
      const int vcol = (r ^ h ^ mqr) & 3;                                     \
      float v[4];                                                             \
      _Pragma("unroll") for (int i = 0; i < 4; ++i)                           \
          v[i] = (ZB)[(mqr * 4 + i) * 1024 + t2 * 256 + h * 64 + vcol * 16 +  \
                      br];                                                    \
      *(float4*)(out + (size_t)((b0 + (TR)*BT + br) * Cc + c_) * Mm + m0 +    \
                 mqr * 4) = make_float4(v[0], v[1], v[2], v[3]);              \
    }                                                                         \
  }

  // P1:[ISSUE, Bf, MFMA, ZW(T), ZR(T-1)] BAR  P2:[STAGE(T+1)] BAR
#define ITER(T, ZBW, ZBR, STC, STN)                                            \
  {                                                                            \
    if ((T) + 2 < NB) ISSUE(STN, (T) + 2)                                      \
    const int rowB = w * BT + (l & 15);                                        \
    const short8 Bf0 = *(const short8*)(                                       \
        xl + rowB * 128 + xsw(rowB, (l >> 4)) * 16);                           \
    const short8 Bf1 = *(const short8*)(                                       \
        xl + rowB * 128 + xsw(rowB, 4 + (l >> 4)) * 16);                       \
    f32x4 acc[4];                                                              \
    _Pragma("unroll") for (int ct = 0; ct < 4; ++ct) acc[ct] =                 \
        (f32x4){0.f, 0.f, 0.f, 0.f};                                           \
    _Pragma("unroll") for (int ct = 0; ct < 4; ++ct) acc[ct] =                 \
        __builtin_amdgcn_mfma_f32_16x16x32_bf16(A[ct][0], Bf0, acc[ct], 0, 0,  \
                                                0);                            \
    _Pragma("unroll") for (int ct = 0; ct < 4; ++ct) acc[ct] =                 \
        __builtin_amdgcn_mfma_f32_16x16x32_bf16(A[ct][1], Bf1, acc[ct], 0, 0,  \
                                                0);                            \
    ZW(ZBW)                                                                    \
    if ((T) > 0) ZR(ZBR, (T)-1)                                                \
    BAR()                                                                      \
    if ((T) + 1 < NB) {                                                        \
      STAGE(STC)                                                               \
      BAR()                                                                    \
    }                                                                          \
  }

  ITER(0, zb0, zb1, st1, st0)
  ITER(1, zb1, zb0, st0, st1)
  ITER(2, zb0, zb1, st1, st0)
  ITER(3, zb1, zb0, st0, st1)
  ITER(4, zb0, zb1, st1, st0)
  ITER(5, zb1, zb0, st0, st1)
  ITER(6, zb0, zb1, st1, st0)
  ITER(7, zb1, zb0, st0, st1)

  // epilogue: last tile's z (written to zb1 in ITER(7), BAR already passed)
  ZR(zb1, 7)

#undef ITER
#undef ZR
#undef ZW
#undef BAR
#undef STAGE
#undef ISSUE
}

extern "C" void kernel_launch(void* const* d_in, const int* in_sizes, int n_in,
                              void* d_out, int out_size, void* d_ws,
                              size_t ws_size, hipStream_t stream) {
  const float* x = (const float*)d_in[0];
  const float* mean = (const float*)d_in[1];
  const float* S = (const float*)d_in[2];
  float* out = (float*)d_out;
  const int nblocks = (Mm / MT) * (Bb / (BT * NB));  // 32 * 8 = 256
  hipLaunchKernelGGL(zca_v13, dim3(nblocks), dim3(1024), LDSB, stream, x,
                     mean, S, out);
}